// Round 12
// baseline (5748.771 us; speedup 1.0000x reference)
//
#include <hip/hip_runtime.h>

// Problem constants (compile-time; from reference: T,B,N,R,E,D = 20,4,50000,4,1600000,5)
namespace {
constexpr int TS = 20;
constexpr int B  = 4;
constexpr int N  = 50000;
constexpr int R  = 4;
constexpr int E  = 1600000;
constexpr int D  = 5;
constexpr int BN = B * N;            // 200000
constexpr float DT = 1.0f;

typedef float f32x4 __attribute__((ext_vector_type(4)));

// Workspace layout. Shared (cross-block) data only:
// zpack: D slots of N bytes (4-bit batch mask per neuron)
// cnt:   TS+D ints (per-step spike counts)
// bar:   arrival counter + epoch flag (grid barrier)
// rec:   [n][b][r] floats (atomic scatter target, consumed+zeroed by owner)
constexpr size_t OFF_ZPACK = 0;
constexpr size_t OFF_CNT   = 250112;                           // 16B-aligned pad
constexpr size_t OFF_BAR   = 250240;                           // 2 ints
constexpr size_t OFF_REC   = 262144;
constexpr size_t ZERO_BYTES = OFF_REC + (size_t)BN * R * 4;    // ~3.46 MB

constexpr int NBLK = (BN + 255) / 256;                         // 782 blocks
}

// Grid barrier: block-internal syncthreads + 1 atomic arrival per block +
// epoch-flag release. Bounded spin: a broken barrier produces wrong results
// (visible failure) instead of a GPU hang (container death).
__device__ __forceinline__ void gbarrier(int* __restrict__ bar_cnt,
                                         int* __restrict__ bar_flag, int epoch) {
  __threadfence();                      // prior writes visible device-wide
  __syncthreads();                      // whole block arrived
  if (threadIdx.x == 0) {
    int old = __hip_atomic_fetch_add(bar_cnt, 1, __ATOMIC_ACQ_REL,
                                     __HIP_MEMORY_SCOPE_AGENT);
    if (old == NBLK - 1) {              // last arriver: reset + release
      __hip_atomic_store(bar_cnt, 0, __ATOMIC_RELAXED, __HIP_MEMORY_SCOPE_AGENT);
      __hip_atomic_store(bar_flag, epoch, __ATOMIC_RELEASE, __HIP_MEMORY_SCOPE_AGENT);
    } else {
      int guard = 0;
      while (__hip_atomic_load(bar_flag, __ATOMIC_ACQUIRE,
                               __HIP_MEMORY_SCOPE_AGENT) < epoch) {
        if (++guard > (1 << 20)) break; // ~70ms cap: fail visibly, never hang
        __builtin_amdgcn_s_sleep(2);
      }
    }
  }
  __syncthreads();
}

// One persistent thread per (neuron, batch): idx = n*4 + b. All recurrent
// state (psc_rise, psc, v, r, asc1, asc2, prev_z) lives in registers across
// the full T=20 scan. Per-step memory: x (streamed, nontemporal), out
// (streamed, nontemporal), one zpack byte per quad, cnt bookkeeping.
// The edge gather runs in-kernel between barriers, only when the D-step
// spike window is non-empty (uniform across blocks -> convergent).
__global__ __launch_bounds__(256, 4) void fused_kernel(
    const f32x4* __restrict__ x,           // (T,B,N) float4 over R
    const int4*  __restrict__ cols4,
    const int*   __restrict__ rows,
    const float* __restrict__ weights,
    const float4* __restrict__ syn_decay,  // N
    const float4* __restrict__ psc_init,   // N
    const float2* __restrict__ asc_amps,   // N
    const float* __restrict__ exp_k1, const float* __restrict__ exp_k2,
    const float* __restrict__ decay,  const float* __restrict__ cur_fac,
    const float* __restrict__ v_th,   const float* __restrict__ e_l,
    const float* __restrict__ v_reset,const float* __restrict__ t_ref,
    const float* __restrict__ param_g,
    unsigned char* __restrict__ zpack,
    int* __restrict__ cnt,                 // TS+D entries, pre-zeroed
    int* __restrict__ bar,                 // [0]=arrival cnt, [1]=epoch flag
    float* __restrict__ rec,               // [n][b][r], pre-zeroed
    float* __restrict__ out) {             // (T,B,N)
  const int idx = blockIdx.x * 256 + threadIdx.x;
  const bool active = idx < BN;
  const int n = idx >> 2;
  const int b = idx & 3;
  int* bar_cnt = bar;
  int* bar_flag = bar + 1;
  __shared__ int s_w0;

  // Per-neuron parameters (quad-uniform; L1 broadcast)
  float4 sd = make_float4(0,0,0,0), pi = make_float4(0,0,0,0);
  float2 amp = make_float2(0,0);
  float k1n=0.f, k2n=0.f, dec=0.f, cfn=0.f, vth=1.f, eln=0.f, vrs=0.f, trf=0.f, pg=0.f;
  if (active) {
    sd = syn_decay[n]; pi = psc_init[n]; amp = asc_amps[n];
    k1n = exp_k1[n]; k2n = exp_k2[n]; dec = decay[n]; cfn = cur_fac[n];
    vth = v_th[n]; eln = e_l[n]; vrs = v_reset[n]; trf = t_ref[n]; pg = param_g[n];
  }
  const float norm = vth - eln;        // normalizer
  const float vgap = vrs - vth;        // v_gap
  const float gg   = pg * eln;         // gathered_g

  // Register-resident recurrent state
  f32x4 pr = {0.f,0.f,0.f,0.f};        // psc_rise
  f32x4 pc = {0.f,0.f,0.f,0.f};        // psc
  float v = eln, rr = 0.f, a1 = 0.f, a2 = 0.f, pz = 0.f;
  bool rec_dirty = false;              // uniform: rec possibly nonzero?
  int epoch = 0;

  f32x4 xx = {0.f,0.f,0.f,0.f};
  if (active) xx = __builtin_nontemporal_load(x + ((size_t)b * N + n));   // x[0]

  for (int t = 0; t < TS; ++t) {
    // Prefetch next step's x; HBM latency hides under compute + barrier.
    f32x4 xn = {0.f,0.f,0.f,0.f};
    if (active && t + 1 < TS)
      xn = __builtin_nontemporal_load(x + ((size_t)(t + 1) * BN + b * N + n));

    float z = 0.f;
    if (active) {
      f32x4 rc = {0.f,0.f,0.f,0.f};
      if (rec_dirty) {                 // uniform; silent steps skip entirely
        // atomic loads: rec was written by other CUs' L2 atomics (L1-bypass)
        rc.x = __hip_atomic_load(rec + idx*4 + 0, __ATOMIC_RELAXED, __HIP_MEMORY_SCOPE_AGENT);
        rc.y = __hip_atomic_load(rec + idx*4 + 1, __ATOMIC_RELAXED, __HIP_MEMORY_SCOPE_AGENT);
        rc.z = __hip_atomic_load(rec + idx*4 + 2, __ATOMIC_RELAXED, __HIP_MEMORY_SCOPE_AGENT);
        rc.w = __hip_atomic_load(rec + idx*4 + 3, __ATOMIC_RELAXED, __HIP_MEMORY_SCOPE_AGENT);
        ((f32x4*)rec)[idx] = (f32x4){0.f,0.f,0.f,0.f};
      }
      // inp = rec + x_t
      const float ix = rc.x + xx.x, iy = rc.y + xx.y, iz = rc.z + xx.z, iw = rc.w + xx.w;
      // new_psc = sd*(psc + psc_rise)   (OLD psc_rise; DT=1)
      const f32x4 npc = { sd.x * (pc.x + pr.x), sd.y * (pc.y + pr.y),
                          sd.z * (pc.z + pr.z), sd.w * (pc.w + pr.w) };
      // new_psc_rise = sd*psc_rise + psc_init*inp
      pr = (f32x4){ sd.x * pr.x + pi.x * ix, sd.y * pr.y + pi.y * iy,
                    sd.z * pr.z + pi.z * iz, sd.w * pr.w + pi.w * iw };
      pc = npc;

      const float I = npc.x + npc.y + npc.z + npc.w;
      const float c1 = I + a1 + a2 + gg;             // OLD asc1/asc2
      a1 = k1n * a1 + pz * amp.x;
      a2 = k2n * a2 + pz * amp.y;
      v = dec * v + cfn * c1 + pz * vgap;

      const float vsc = (v - vth) / norm;
      z = (vsc > 0.f) ? 1.0f : 0.0f;
      if (rr > 0.f) z = 0.0f;                        // refractory mask
      rr = fminf(fmaxf(rr + z * trf - DT, 0.f), trf);

      __builtin_nontemporal_store(z, out + ((size_t)t * BN + b * N + n));
      pz = z;                                        // prev_z for t+1, in-register
    }

    // Publish this step's spike mask for future gathers.
    const int head    = (D - (t % D)) % D;
    const int newslot = (head + D - 1) % D;
    const unsigned long long bal = __ballot(z != 0.f);
    if (active && b == 0) {
      const unsigned lane = threadIdx.x & 63;        // idx&3 == lane&3
      const unsigned char m = (unsigned char)((bal >> (lane & ~3u)) & 0xFull);
      zpack[newslot * N + n] = m;
      if (m) atomicAdd(&cnt[t + D], 1);              // device-scope
    }

    if (t + 1 < TS) {
      gbarrier(bar_cnt, bar_flag, ++epoch);          // step t fully published

      // Spike window for step t+1 = cnt[t+1..t+5] (z_{t-4}..z_t counts).
      // One L1-bypassing read per block -> LDS; uniform across blocks
      // (all window writes happened before the barrier).
      if (threadIdx.x == 0) {
        int w = 0;
#pragma unroll
        for (int i = 1; i <= D; ++i)
          w += __hip_atomic_load(&cnt[t + i], __ATOMIC_RELAXED, __HIP_MEMORY_SCOPE_AGENT);
        s_w0 = w;
      }
      __syncthreads();
      const int w0 = s_w0;

      if (w0 > 0) {
        const int headn = (D - ((t + 1) % D)) % D;
        if (active) {
#pragma unroll
          for (int h = 0; h < 2; ++h) {              // 8 edges per thread
            const int q = idx * 2 + h;
            const int4 c4 = cols4[q];
#pragma unroll
            for (int j = 0; j < 4; ++j) {
              const int c = (j==0) ? c4.x : (j==1) ? c4.y : (j==2) ? c4.z : c4.w;
              int d = c / N;                         // magic-mul
              const int ns = c - d * N;
              int slot = headn + d; if (slot >= D) slot -= D;
              const unsigned char m = __hip_atomic_load(
                  &zpack[slot * N + ns], __ATOMIC_RELAXED, __HIP_MEMORY_SCOPE_AGENT);
              if (m) {
                const int e = q * 4 + j;
                const float w = weights[e];
                const int row = rows[e];
                float* base = rec + ((row & ~3) << 2) + (row & 3);  // [n][b][r]
                if (m & 1) atomicAdd(base + 0,  w);
                if (m & 2) atomicAdd(base + 4,  w);
                if (m & 4) atomicAdd(base + 8,  w);
                if (m & 8) atomicAdd(base + 12, w);
              }
            }
          }
        }
        gbarrier(bar_cnt, bar_flag, ++epoch);        // rec complete
        rec_dirty = true;
      } else {
        rec_dirty = false;
      }
    }
    xx = xn;
  }
}

extern "C" void kernel_launch(void* const* d_in, const int* in_sizes, int n_in,
                              void* d_out, int out_size, void* d_ws, size_t ws_size,
                              hipStream_t stream) {
  const f32x4* x        = (const f32x4*)d_in[0];   // (T,B,N,R)
  const float* weights  = (const float*)d_in[1];
  const float4* syn_dec = (const float4*)d_in[2];
  const float4* psc_ini = (const float4*)d_in[3];
  const float2* asc_amp = (const float2*)d_in[4];
  const float* exp_k1   = (const float*)d_in[5];
  const float* exp_k2   = (const float*)d_in[6];
  const float* decay    = (const float*)d_in[7];
  const float* cur_fac  = (const float*)d_in[8];
  const float* v_th     = (const float*)d_in[9];
  const float* e_l      = (const float*)d_in[10];
  const float* v_reset  = (const float*)d_in[11];
  const float* t_ref    = (const float*)d_in[12];
  const float* param_g  = (const float*)d_in[13];
  // d_in[14] = dampening (backward-only, unused)
  const int* rows       = (const int*)d_in[15];
  const int4* cols4     = (const int4*)d_in[16];

  char* ws = (char*)d_ws;
  unsigned char* zpack = (unsigned char*)(ws + OFF_ZPACK);
  int*   cnt = (int*)(ws + OFF_CNT);
  int*   bar = (int*)(ws + OFF_BAR);
  float* rec = (float*)(ws + OFF_REC);
  float* out = (float*)d_out;

  // Zero shared state incl. barrier words (ws poisoned 0xAA each timed call).
  (void)hipMemsetAsync(ws, 0, ZERO_BYTES, stream);

  fused_kernel<<<NBLK, 256, 0, stream>>>(
      x, cols4, rows, weights, syn_dec, psc_ini, asc_amp,
      exp_k1, exp_k2, decay, cur_fac, v_th, e_l, v_reset, t_ref, param_g,
      zpack, cnt, bar, rec, out);
}

// Round 14
// 1188.543 us; speedup vs baseline: 4.8368x; 4.8368x over previous
//
#include <hip/hip_runtime.h>

// Problem constants (reference: T,B,N,R,E,D = 20,4,50000,4,1600000,5)
namespace {
constexpr int TS = 20;
constexpr int B  = 4;
constexpr int N  = 50000;
constexpr int R  = 4;
constexpr int E  = 1600000;
constexpr int D  = 5;
constexpr int BN = B * N;              // 200000
constexpr int TPB    = 1024;
constexpr int NBLK   = 100;            // 1 block/CU max -> co-residency guaranteed
constexpr int STRIDE = NBLK * TPB;     // 102400 (STRIDE % 4 == 0: quad alignment holds)
constexpr int NG = 10, GSZ = 10;       // barrier fan-in: 10 groups x 10 blocks
constexpr float DT = 1.0f;

typedef float f32x4 __attribute__((ext_vector_type(4)));

// Workspace: zpack as INT lanes (native 4B atomics; byte atomics may CAS-loop).
// Barrier lines padded to 256B each: [0]=flag, [64]=root, [128+g*64]=group g.
constexpr size_t OFF_ZPACK = 0;                               // D*N ints = 1,000,000 B
constexpr size_t OFF_CNT   = 1000000;                         // (TS+D) ints
constexpr size_t OFF_BARS  = 1000448;                         // 256B-aligned, 12 lines
constexpr size_t OFF_REC   = 1048576;                         // BN*R floats = 3.2 MB
constexpr size_t ZERO_BYTES = OFF_REC + (size_t)BN * R * 4;   // 4,248,576
}

// Arrival + wait, thread0-of-block only. Monotonic epoch counters (no resets).
// Release/acquire ride the RMW chain: leaf ACQ_REL -> root ACQ_REL -> flag
// RELEASE -> poller ACQUIRE. No __threadfence anywhere. Bounded spin: a broken
// barrier fails visibly instead of hanging the container.
__device__ __forceinline__ void arrive_wait(int* __restrict__ bars, int ep) {
  const int g = blockIdx.x / GSZ;
  int old = __hip_atomic_fetch_add(&bars[128 + g * 64], 1, __ATOMIC_ACQ_REL,
                                   __HIP_MEMORY_SCOPE_AGENT);
  if (old == ep * GSZ - 1) {                       // last in group
    int old2 = __hip_atomic_fetch_add(&bars[64], 1, __ATOMIC_ACQ_REL,
                                      __HIP_MEMORY_SCOPE_AGENT);
    if (old2 == ep * NG - 1)                       // last group
      __hip_atomic_store(&bars[0], ep, __ATOMIC_RELEASE, __HIP_MEMORY_SCOPE_AGENT);
  }
  int guard = 0;
  while (__hip_atomic_load(&bars[0], __ATOMIC_RELAXED, __HIP_MEMORY_SCOPE_AGENT) < ep) {
    if (++guard > (1 << 18)) break;                // fail visibly, never hang
    __builtin_amdgcn_s_sleep(16);                  // ~1k cycles backoff
  }
  (void)__hip_atomic_load(&bars[0], __ATOMIC_ACQUIRE, __HIP_MEMORY_SCOPE_AGENT);
}

// Persistent kernel: thread handles items {gid, gid+STRIDE}, item = n*4+b.
// All recurrent state in registers for all 20 steps. Silent-path per step:
// x load + out store (both nontemporal) + one hierarchical barrier. No shared
// stores at all when no spikes (zpack write skipped unless mask!=0 or the
// slot's previous occupant step had spikes, known from cnt[t]).
__global__ __launch_bounds__(TPB) void fused_kernel(
    const f32x4* __restrict__ x,           // (T,B,N) float4 over R
    const int4*  __restrict__ cols4,
    const int*   __restrict__ rows,
    const float* __restrict__ weights,
    const float4* __restrict__ syn_decay,  // N
    const float4* __restrict__ psc_init,   // N
    const float2* __restrict__ asc_amps,   // N
    const float* __restrict__ exp_k1, const float* __restrict__ exp_k2,
    const float* __restrict__ decay,  const float* __restrict__ cur_fac,
    const float* __restrict__ v_th,   const float* __restrict__ e_l,
    const float* __restrict__ v_reset,const float* __restrict__ t_ref,
    const float* __restrict__ param_g,
    int* __restrict__ zpack,               // D*N ints (4-bit batch mask)
    int* __restrict__ cnt,                 // TS+D ints, pre-zeroed
    int* __restrict__ bars,                // padded barrier lines, pre-zeroed
    float* __restrict__ rec,               // [n][b][r] floats, pre-zeroed
    float* __restrict__ out) {             // (T,B,N)
  const int gid = blockIdx.x * TPB + threadIdx.x;
  __shared__ int s_w0, s_c0;
  if (threadIdx.x == 0) { s_w0 = 0; s_c0 = 0; }

  const int  ii[2]  = { gid, gid + STRIDE };
  const bool act[2] = { true, gid + STRIDE < BN };   // item0 always < BN
  int nn[2], bb[2];
#pragma unroll
  for (int k = 0; k < 2; ++k) {
    const int i = act[k] ? ii[k] : 0;
    nn[k] = i >> 2; bb[k] = i & 3;
  }

  float4 sd[2], pi[2]; float2 amp[2];
  float k1[2], k2[2], dc[2], cf[2], vt[2], el[2], vr[2], tr[2], pg[2];
  float norm[2], vgap[2], gg[2];
#pragma unroll
  for (int k = 0; k < 2; ++k) {
    sd[k] = syn_decay[nn[k]]; pi[k] = psc_init[nn[k]]; amp[k] = asc_amps[nn[k]];
    k1[k] = exp_k1[nn[k]]; k2[k] = exp_k2[nn[k]]; dc[k] = decay[nn[k]];
    cf[k] = cur_fac[nn[k]]; vt[k] = v_th[nn[k]]; el[k] = e_l[nn[k]];
    vr[k] = v_reset[nn[k]]; tr[k] = t_ref[nn[k]]; pg[k] = param_g[nn[k]];
    norm[k] = vt[k] - el[k]; vgap[k] = vr[k] - vt[k]; gg[k] = pg[k] * el[k];
  }

  f32x4 pr[2] = {{0,0,0,0},{0,0,0,0}};   // psc_rise
  f32x4 pc[2] = {{0,0,0,0},{0,0,0,0}};   // psc
  float vv[2] = { el[0], el[1] };
  float rfr[2] = {0,0}, a1[2] = {0,0}, a2[2] = {0,0}, pz[2] = {0,0};

  f32x4 xx[2] = {{0,0,0,0},{0,0,0,0}};
#pragma unroll
  for (int k = 0; k < 2; ++k)
    if (act[k]) xx[k] = __builtin_nontemporal_load(x + ((size_t)bb[k] * N + nn[k]));

  __syncthreads();                        // s_w0/s_c0 init visible
  int ep = 0;

  for (int t = 0; t < TS; ++t) {
    const int w0 = s_w0;                  // spikes in window for step t (uniform)
    const int c0 = s_c0;                  // cnt[t]: prev occupant of newslot
    const int head    = (D - (t % D)) % D;
    const int newslot = (head + D - 1) % D;

    f32x4 xn[2] = {{0,0,0,0},{0,0,0,0}};
#pragma unroll
    for (int k = 0; k < 2; ++k)
      if (act[k] && t + 1 < TS)
        xn[k] = __builtin_nontemporal_load(x + ((size_t)(t + 1) * BN + bb[k] * N + nn[k]));

    float zz[2] = {0.f, 0.f};
#pragma unroll
    for (int k = 0; k < 2; ++k) {
      if (!act[k]) continue;
      f32x4 rc = {0,0,0,0};
      if (w0 > 0) {                        // uniform; silent steps skip entirely
        float* rp = rec + (size_t)ii[k] * 4;
        rc.x = __hip_atomic_load(rp + 0, __ATOMIC_RELAXED, __HIP_MEMORY_SCOPE_AGENT);
        rc.y = __hip_atomic_load(rp + 1, __ATOMIC_RELAXED, __HIP_MEMORY_SCOPE_AGENT);
        rc.z = __hip_atomic_load(rp + 2, __ATOMIC_RELAXED, __HIP_MEMORY_SCOPE_AGENT);
        rc.w = __hip_atomic_load(rp + 3, __ATOMIC_RELAXED, __HIP_MEMORY_SCOPE_AGENT);
        // atomic zero-stores: coherent vs next gather's cross-XCD atomics
        __hip_atomic_store(rp + 0, 0.f, __ATOMIC_RELAXED, __HIP_MEMORY_SCOPE_AGENT);
        __hip_atomic_store(rp + 1, 0.f, __ATOMIC_RELAXED, __HIP_MEMORY_SCOPE_AGENT);
        __hip_atomic_store(rp + 2, 0.f, __ATOMIC_RELAXED, __HIP_MEMORY_SCOPE_AGENT);
        __hip_atomic_store(rp + 3, 0.f, __ATOMIC_RELAXED, __HIP_MEMORY_SCOPE_AGENT);
      }
      const float ix = rc.x + xx[k].x, iy = rc.y + xx[k].y;
      const float iz = rc.z + xx[k].z, iw = rc.w + xx[k].w;
      const f32x4 npc = { sd[k].x * (pc[k].x + pr[k].x), sd[k].y * (pc[k].y + pr[k].y),
                          sd[k].z * (pc[k].z + pr[k].z), sd[k].w * (pc[k].w + pr[k].w) };
      pr[k] = (f32x4){ sd[k].x * pr[k].x + pi[k].x * ix, sd[k].y * pr[k].y + pi[k].y * iy,
                       sd[k].z * pr[k].z + pi[k].z * iz, sd[k].w * pr[k].w + pi[k].w * iw };
      pc[k] = npc;
      const float I  = npc.x + npc.y + npc.z + npc.w;
      const float c1 = I + a1[k] + a2[k] + gg[k];          // OLD asc1/asc2
      a1[k] = k1[k] * a1[k] + pz[k] * amp[k].x;
      a2[k] = k2[k] * a2[k] + pz[k] * amp[k].y;
      vv[k] = dc[k] * vv[k] + cf[k] * c1 + pz[k] * vgap[k];
      const float vsc = (vv[k] - vt[k]) / norm[k];
      float z = (vsc > 0.f) ? 1.0f : 0.0f;
      if (rfr[k] > 0.f) z = 0.0f;                          // refractory mask
      rfr[k] = fminf(fmaxf(rfr[k] + z * tr[k] - DT, 0.f), tr[k]);
      __builtin_nontemporal_store(z, out + ((size_t)t * BN + bb[k] * N + nn[k]));
      pz[k] = z;
      zz[k] = z;
    }

    // Publish spike masks (quad = 4 adjacent lanes; leader lane%4==0 for both items).
#pragma unroll
    for (int k = 0; k < 2; ++k) {
      const unsigned long long bal = __ballot(zz[k] != 0.f);
      if (act[k] && bb[k] == 0) {
        const unsigned lane = threadIdx.x & 63;
        const int m = (int)((bal >> (lane & ~3u)) & 0xFull);
        if (m | c0)                        // skip store when slot stays all-zero
          __hip_atomic_store(&zpack[newslot * N + nn[k]], m, __ATOMIC_RELAXED,
                             __HIP_MEMORY_SCOPE_AGENT);
        if (m) atomicAdd(&cnt[t + D], 1);
      }
    }

    if (t + 1 == TS) break;

    // ---- grid barrier (step t fully published) ----
    __syncthreads();                       // drains vmcnt: atomics performed
    ++ep;
    if (threadIdx.x == 0) {
      arrive_wait(bars, ep);
      int w = 0;
#pragma unroll
      for (int i = 1; i <= D; ++i)         // window(t+1) = cnt[t+1 .. t+5]
        w += __hip_atomic_load(&cnt[t + i], __ATOMIC_RELAXED, __HIP_MEMORY_SCOPE_AGENT);
      s_w0 = w;
      s_c0 = __hip_atomic_load(&cnt[t + 1], __ATOMIC_RELAXED, __HIP_MEMORY_SCOPE_AGENT);
    }
    __syncthreads();

    if (s_w0 > 0) {                        // gather for step t+1 (uniform)
      const int headn = (D - ((t + 1) % D)) % D;
#pragma unroll
      for (int h = 0; h < 4; ++h) {        // 16 edges/thread
        const int q = gid + h * STRIDE;
        if (q < E / 4) {
          const int4 c4 = cols4[q];
#pragma unroll
          for (int j = 0; j < 4; ++j) {
            const int c = (j==0) ? c4.x : (j==1) ? c4.y : (j==2) ? c4.z : c4.w;
            int d = c / N;                 // magic-mul
            const int ns = c - d * N;
            int slot = headn + d; if (slot >= D) slot -= D;
            const int m = __hip_atomic_load(&zpack[slot * N + ns], __ATOMIC_RELAXED,
                                            __HIP_MEMORY_SCOPE_AGENT);
            if (m) {
              const int e = q * 4 + j;
              const float w = weights[e];
              const int row = rows[e];
              float* base = rec + ((row & ~3) << 2) + (row & 3);   // [n][b][r]
              if (m & 1) atomicAdd(base + 0,  w);
              if (m & 2) atomicAdd(base + 4,  w);
              if (m & 4) atomicAdd(base + 8,  w);
              if (m & 8) atomicAdd(base + 12, w);
            }
          }
        }
      }
      __syncthreads();                     // drains gather atomics
      ++ep;
      if (threadIdx.x == 0) arrive_wait(bars, ep);   // rec complete
      __syncthreads();
    }

    xx[0] = xn[0]; xx[1] = xn[1];
  }
}

extern "C" void kernel_launch(void* const* d_in, const int* in_sizes, int n_in,
                              void* d_out, int out_size, void* d_ws, size_t ws_size,
                              hipStream_t stream) {
  const f32x4* x        = (const f32x4*)d_in[0];   // (T,B,N,R)
  const float* weights  = (const float*)d_in[1];
  const float4* syn_dec = (const float4*)d_in[2];
  const float4* psc_ini = (const float4*)d_in[3];
  const float2* asc_amp = (const float2*)d_in[4];
  const float* exp_k1   = (const float*)d_in[5];
  const float* exp_k2   = (const float*)d_in[6];
  const float* decay    = (const float*)d_in[7];
  const float* cur_fac  = (const float*)d_in[8];
  const float* v_th     = (const float*)d_in[9];
  const float* e_l      = (const float*)d_in[10];
  const float* v_reset  = (const float*)d_in[11];
  const float* t_ref    = (const float*)d_in[12];
  const float* param_g  = (const float*)d_in[13];
  // d_in[14] = dampening (backward-only, unused)
  const int* rows       = (const int*)d_in[15];
  const int4* cols4     = (const int4*)d_in[16];

  char* ws = (char*)d_ws;
  int*   zpack = (int*)(ws + OFF_ZPACK);
  int*   cnt   = (int*)(ws + OFF_CNT);
  int*   bars  = (int*)(ws + OFF_BARS);
  float* rec   = (float*)(ws + OFF_REC);
  float* out   = (float*)d_out;

  // Zero shared state incl. barrier lines (ws poisoned 0xAA each timed call).
  (void)hipMemsetAsync(ws, 0, ZERO_BYTES, stream);

  fused_kernel<<<NBLK, TPB, 0, stream>>>(
      x, cols4, rows, weights, syn_dec, psc_ini, asc_amp,
      exp_k1, exp_k2, decay, cur_fac, v_th, e_l, v_reset, t_ref, param_g,
      zpack, cnt, bars, rec, out);
}